// Round 1
// baseline (899.932 us; speedup 1.0000x reference)
//
#include <hip/hip_runtime.h>
#include <hip/hip_bf16.h>
#include <stdint.h>

// Problem constants
#define BB 4
#define SS 2048
#define DD 1024
#define HH 16
#define DHH 128   // per-head dim after concat (2*64)

typedef __bf16 bf16x8 __attribute__((ext_vector_type(8)));
typedef __bf16 bf16x4 __attribute__((ext_vector_type(4)));
typedef float  f32x4  __attribute__((ext_vector_type(4)));

// ---------------------------------------------------------------------------
// Cast fp32 -> bf16, 4 elems/thread
__global__ void cast_bf16_kernel(const float* __restrict__ in, __bf16* __restrict__ out, int n) {
    int i = (blockIdx.x * blockDim.x + threadIdx.x) * 4;
    if (i < n) {
        f32x4 v = *(const f32x4*)(in + i);
        bf16x4 o;
        o[0] = (__bf16)v[0]; o[1] = (__bf16)v[1]; o[2] = (__bf16)v[2]; o[3] = (__bf16)v[3];
        *(bf16x4*)(out + i) = o;
    }
}

// ---------------------------------------------------------------------------
// Transpose + cast: W[K][N] fp32 -> Wt[N][K] bf16.  K,N multiples of 32.
__global__ void transpose_cast_kernel(const float* __restrict__ in, __bf16* __restrict__ out,
                                      int K, int N) {
    __shared__ float tile[32][33];
    int n0 = blockIdx.x * 32, k0 = blockIdx.y * 32;
    int tx = threadIdx.x, ty = threadIdx.y;   // 32 x 8
    #pragma unroll
    for (int i = 0; i < 32; i += 8)
        tile[ty + i][tx] = in[(size_t)(k0 + ty + i) * N + n0 + tx];
    __syncthreads();
    #pragma unroll
    for (int i = 0; i < 32; i += 8)
        out[(size_t)(n0 + ty + i) * K + k0 + tx] = (__bf16)tile[tx][ty + i];
}

// ---------------------------------------------------------------------------
// GEMM: C[M][N] = A[M][K] @ Bt[N][K]^T   (both bf16 row-major, contiguous in K)
// 128x128 tile, BK=32, 256 threads = 4 waves (2x2), each wave 4x4 16x16 subtiles.
// EPI 0: write bf16 into QKV buffer [B,H,S,128] head-interleaved at +qkv_off
// EPI 1: write fp32 to out[M][1024] with bias
template <int EPI>
__global__ void gemm128_kernel(const __bf16* __restrict__ A, const __bf16* __restrict__ Bt,
                               int M, int K, void* __restrict__ outp, int qkv_off,
                               const float* __restrict__ bias) {
    __shared__ __bf16 As[128][40];  // +8 pad: 2-way max conflicts
    __shared__ __bf16 Bs[128][40];
    const int t = threadIdx.x;
    const int wave = t >> 6, lane = t & 63;
    const int l15 = lane & 15, quad = lane >> 4;
    const int wm = (wave & 1) * 64, wn = (wave >> 1) * 64;
    const int m0 = blockIdx.x * 128, n0 = blockIdx.y * 128;
    const int r  = t >> 2;            // 0..63 staging row
    const int cg = (t & 3) * 8;       // staging col group

    f32x4 acc[4][4] = {};

    for (int k0 = 0; k0 < K; k0 += 32) {
        #pragma unroll
        for (int i = 0; i < 2; ++i) {
            int row = r + i * 64;
            bf16x8 av = *(const bf16x8*)(A  + (size_t)(m0 + row) * K + k0 + cg);
            *(bf16x8*)&As[row][cg] = av;
            bf16x8 bv = *(const bf16x8*)(Bt + (size_t)(n0 + row) * K + k0 + cg);
            *(bf16x8*)&Bs[row][cg] = bv;
        }
        __syncthreads();
        bf16x8 af[4], bf[4];
        #pragma unroll
        for (int i = 0; i < 4; ++i) af[i] = *(const bf16x8*)&As[wm + i * 16 + l15][quad * 8];
        #pragma unroll
        for (int i = 0; i < 4; ++i) bf[i] = *(const bf16x8*)&Bs[wn + i * 16 + l15][quad * 8];
        #pragma unroll
        for (int mi = 0; mi < 4; ++mi)
            #pragma unroll
            for (int ni = 0; ni < 4; ++ni)
                acc[mi][ni] = __builtin_amdgcn_mfma_f32_16x16x32_bf16(af[mi], bf[ni], acc[mi][ni], 0, 0, 0);
        __syncthreads();
    }

    // epilogue: C row = quad*4+rr, col = l15 within each 16x16 subtile
    #pragma unroll
    for (int mi = 0; mi < 4; ++mi) {
        #pragma unroll
        for (int ni = 0; ni < 4; ++ni) {
            #pragma unroll
            for (int rr = 0; rr < 4; ++rr) {
                int m = m0 + wm + mi * 16 + quad * 4 + rr;
                int n = n0 + wn + ni * 16 + l15;
                if (EPI == 0) {
                    int b = m >> 11, s = m & 2047;      // S=2048
                    int h = n >> 6,  d = n & 63;
                    __bf16* q = (__bf16*)outp;
                    q[(((size_t)b * HH + h) * SS + s) * DHH + d + qkv_off] = (__bf16)acc[mi][ni][rr];
                } else {
                    float* o = (float*)outp;
                    o[(size_t)m * 1024 + n] = acc[mi][ni][rr] + bias[n];
                }
            }
        }
    }
}

// ---------------------------------------------------------------------------
// Flash attention, non-causal. Q,K,V: [B*H][S][128] bf16. O: [B][S][H*128] bf16.
// Block: 256 thr = 4 waves; Q tile 128 rows (wave owns 32); KV tile 64.
__global__ __launch_bounds__(256, 2)
void attn_kernel(const __bf16* __restrict__ Q, const __bf16* __restrict__ Kb,
                 const __bf16* __restrict__ Vb, __bf16* __restrict__ O) {
    __shared__ __bf16 Ks[64][136];   // [kv][d]  stride 272B (16B-aligned, 2-way free)
    __shared__ __bf16 Vt[128][72];   // [d][kv]  stride 144B
    __shared__ __bf16 Ps[128][72];   // [m][kv]

    const int t = threadIdx.x;
    const int wave = t >> 6, lane = t & 63;
    const int l15 = lane & 15, quad = lane >> 4;
    const int bh = blockIdx.y;                 // 0..63
    const int b = bh >> 4, h = bh & 15;
    const int mt = blockIdx.x;                 // 0..15 (q tile)
    const size_t base = (size_t)bh * SS * DHH;

    // preload Q fragments (A-operand layout): rows wave*32..+32
    bf16x8 qf[2][4];
    #pragma unroll
    for (int ms = 0; ms < 2; ++ms) {
        int row = mt * 128 + wave * 32 + ms * 16 + l15;
        #pragma unroll
        for (int ks = 0; ks < 4; ++ks)
            qf[ms][ks] = *(const bf16x8*)(Q + base + (size_t)row * DHH + ks * 32 + quad * 8);
    }

    f32x4 oacc[2][8] = {};
    float mi_[2][4], li_[2][4];
    #pragma unroll
    for (int a = 0; a < 2; ++a)
        #pragma unroll
        for (int rr = 0; rr < 4; ++rr) { mi_[a][rr] = -1e30f; li_[a][rr] = 0.f; }

    const float SL2E = 0.125f * 1.44269504088896f;  // (1/sqrt(64)) * log2(e)

    for (int kt = 0; kt < SS / 64; ++kt) {
        // stage K tile + transposed V tile
        #pragma unroll
        for (int j = 0; j < 4; ++j) {
            int chunk = t + j * 256;
            int row = chunk >> 4;            // kv 0..63
            int col = (chunk & 15) * 8;      // d  0..120
            const __bf16* kp = Kb + base + (size_t)(kt * 64 + row) * DHH + col;
            bf16x8 kv8 = *(const bf16x8*)kp;
            *(bf16x8*)&Ks[row][col] = kv8;
            const __bf16* vp = Vb + base + (size_t)(kt * 64 + row) * DHH + col;
            bf16x8 vv = *(const bf16x8*)vp;
            #pragma unroll
            for (int e = 0; e < 8; ++e) Vt[col + e][row] = vv[e];
        }
        __syncthreads();

        // S = Q K^T  (per wave: 2 m-subtiles x 4 n-subtiles)
        f32x4 sc[2][4] = {};
        #pragma unroll
        for (int kst = 0; kst < 4; ++kst) {
            bf16x8 bfr[4];
            #pragma unroll
            for (int ns = 0; ns < 4; ++ns)
                bfr[ns] = *(const bf16x8*)&Ks[ns * 16 + l15][kst * 32 + quad * 8];
            #pragma unroll
            for (int ms = 0; ms < 2; ++ms)
                #pragma unroll
                for (int ns = 0; ns < 4; ++ns)
                    sc[ms][ns] = __builtin_amdgcn_mfma_f32_16x16x32_bf16(qf[ms][kst], bfr[ns], sc[ms][ns], 0, 0, 0);
        }

        // online softmax (exp2 domain), rows = quad*4+rr, 16 lanes share a row
        #pragma unroll
        for (int ms = 0; ms < 2; ++ms) {
            #pragma unroll
            for (int rr = 0; rr < 4; ++rr) {
                float vmax = -1e30f;
                #pragma unroll
                for (int ns = 0; ns < 4; ++ns) vmax = fmaxf(vmax, sc[ms][ns][rr]);
                vmax *= SL2E;
                #pragma unroll
                for (int off = 1; off < 16; off <<= 1) vmax = fmaxf(vmax, __shfl_xor(vmax, off));
                float mnew = fmaxf(mi_[ms][rr], vmax);
                float alpha = exp2f(mi_[ms][rr] - mnew);
                mi_[ms][rr] = mnew;
                float rsum = 0.f;
                #pragma unroll
                for (int ns = 0; ns < 4; ++ns) {
                    float p = exp2f(sc[ms][ns][rr] * SL2E - mnew);
                    sc[ms][ns][rr] = p;
                    rsum += p;
                }
                #pragma unroll
                for (int off = 1; off < 16; off <<= 1) rsum += __shfl_xor(rsum, off);
                li_[ms][rr] = li_[ms][rr] * alpha + rsum;
                #pragma unroll
                for (int ds = 0; ds < 8; ++ds) oacc[ms][ds][rr] *= alpha;
            }
            // P -> LDS (own 32-row strip only; wave-local, no barrier needed)
            #pragma unroll
            for (int ns = 0; ns < 4; ++ns)
                #pragma unroll
                for (int rr = 0; rr < 4; ++rr)
                    Ps[wave * 32 + ms * 16 + quad * 4 + rr][ns * 16 + l15] = (__bf16)sc[ms][ns][rr];
        }

        // O += P V   (k = kv, 2 ksteps of 32; n = d, 8 subtiles)
        #pragma unroll
        for (int kst = 0; kst < 2; ++kst) {
            bf16x8 af2[2];
            #pragma unroll
            for (int ms = 0; ms < 2; ++ms)
                af2[ms] = *(const bf16x8*)&Ps[wave * 32 + ms * 16 + l15][kst * 32 + quad * 8];
            #pragma unroll
            for (int ds = 0; ds < 8; ++ds) {
                bf16x8 bfr = *(const bf16x8*)&Vt[ds * 16 + l15][kst * 32 + quad * 8];
                #pragma unroll
                for (int ms = 0; ms < 2; ++ms)
                    oacc[ms][ds] = __builtin_amdgcn_mfma_f32_16x16x32_bf16(af2[ms], bfr, oacc[ms][ds], 0, 0, 0);
            }
        }
        __syncthreads();
    }

    // epilogue: O[b][s][h*128 + d], normalized
    #pragma unroll
    for (int ms = 0; ms < 2; ++ms) {
        #pragma unroll
        for (int rr = 0; rr < 4; ++rr) {
            float inv = 1.f / li_[ms][rr];
            int s = mt * 128 + wave * 32 + ms * 16 + quad * 4 + rr;
            size_t ob = ((size_t)b * SS + s) * (HH * DHH) + (size_t)h * DHH;
            #pragma unroll
            for (int ds = 0; ds < 8; ++ds)
                O[ob + ds * 16 + l15] = (__bf16)(oacc[ms][ds][rr] * inv);
        }
    }
}

// ---------------------------------------------------------------------------
extern "C" void kernel_launch(void* const* d_in, const int* in_sizes, int n_in,
                              void* d_out, int out_size, void* d_ws, size_t ws_size,
                              hipStream_t stream) {
    const float* x      = (const float*)d_in[0];
    const float* c      = (const float*)d_in[1];
    const float* Wq_x   = (const float*)d_in[2];
    const float* Wk_x   = (const float*)d_in[3];
    const float* Wv_x   = (const float*)d_in[4];
    const float* Wq_c   = (const float*)d_in[5];
    const float* Wk_c   = (const float*)d_in[6];
    const float* Wv_c   = (const float*)d_in[7];
    const float* W_proj = (const float*)d_in[8];
    const float* b_proj = (const float*)d_in[9];

    const size_t nXC = (size_t)BB * SS * DD;          // 8388608
    const size_t nW  = (size_t)DD * DD;               // 1048576
    const size_t nWP = (size_t)(2 * HH * 64) * DD;    // 2097152 (2048x1024)
    const size_t nQKV = (size_t)BB * HH * SS * DHH;   // 16777216

    __bf16* ws  = (__bf16*)d_ws;
    __bf16* xb  = ws;                 // 8.4M  (reused as O later)
    __bf16* cb  = xb + nXC;           // 8.4M
    __bf16* wt0 = cb + nXC;           // Wq_x^T
    __bf16* wt1 = wt0 + nW;           // Wk_x^T
    __bf16* wt2 = wt1 + nW;           // Wv_x^T
    __bf16* wt3 = wt2 + nW;           // Wq_c^T
    __bf16* wt4 = wt3 + nW;           // Wk_c^T
    __bf16* wt5 = wt4 + nW;           // Wv_c^T
    __bf16* wtp = wt5 + nW;           // W_proj^T [1024][2048]
    __bf16* Qb  = wtp + nWP;
    __bf16* Kb  = Qb + nQKV;
    __bf16* Vb  = Kb + nQKV;
    __bf16* Ob  = xb;                 // alias x/c region (dead after QKV GEMMs)

    // 1. casts
    cast_bf16_kernel<<<(int)(nXC / 1024), 256, 0, stream>>>(x, xb, (int)nXC);
    cast_bf16_kernel<<<(int)(nXC / 1024), 256, 0, stream>>>(c, cb, (int)nXC);

    // 2. weight transposes ([K][N] -> [N][K] bf16)
    transpose_cast_kernel<<<dim3(32, 32), dim3(32, 8), 0, stream>>>(Wq_x, wt0, 1024, 1024);
    transpose_cast_kernel<<<dim3(32, 32), dim3(32, 8), 0, stream>>>(Wk_x, wt1, 1024, 1024);
    transpose_cast_kernel<<<dim3(32, 32), dim3(32, 8), 0, stream>>>(Wv_x, wt2, 1024, 1024);
    transpose_cast_kernel<<<dim3(32, 32), dim3(32, 8), 0, stream>>>(Wq_c, wt3, 1024, 1024);
    transpose_cast_kernel<<<dim3(32, 32), dim3(32, 8), 0, stream>>>(Wk_c, wt4, 1024, 1024);
    transpose_cast_kernel<<<dim3(32, 32), dim3(32, 8), 0, stream>>>(Wv_c, wt5, 1024, 1024);
    transpose_cast_kernel<<<dim3(32, 64), dim3(32, 8), 0, stream>>>(W_proj, wtp, 2048, 1024);

    // 3. QKV GEMMs (M=8192, K=1024, N=1024), head-interleaved epilogue
    dim3 gg(64, 8);
    gemm128_kernel<0><<<gg, 256, 0, stream>>>(xb, wt0, 8192, 1024, Qb, 0,  nullptr);
    gemm128_kernel<0><<<gg, 256, 0, stream>>>(cb, wt3, 8192, 1024, Qb, 64, nullptr);
    gemm128_kernel<0><<<gg, 256, 0, stream>>>(xb, wt1, 8192, 1024, Kb, 0,  nullptr);
    gemm128_kernel<0><<<gg, 256, 0, stream>>>(cb, wt4, 8192, 1024, Kb, 64, nullptr);
    gemm128_kernel<0><<<gg, 256, 0, stream>>>(xb, wt2, 8192, 1024, Vb, 0,  nullptr);
    gemm128_kernel<0><<<gg, 256, 0, stream>>>(cb, wt5, 8192, 1024, Vb, 64, nullptr);

    // 4. attention (writes Ob = [B,S,H*128] bf16)
    attn_kernel<<<dim3(16, 64), 256, 0, stream>>>(Qb, Kb, Vb, Ob);

    // 5. projection (M=8192, K=2048, N=1024) + bias -> fp32 out
    gemm128_kernel<1><<<dim3(64, 8), 256, 0, stream>>>(Ob, wtp, 8192, 2048, d_out, 0, b_proj);
}